// Round 18
// baseline (742.282 us; speedup 1.0000x reference)
//
#include <hip/hip_runtime.h>
#include <hip/hip_bf16.h>

#define B_    2
#define H_    90
#define W_    180
#define C_    768
#define WFK   46          // kept W-frequency modes (of 91)
#define NBK   8
#define BSK   96
#define HID   3072
#define NTOK  (B_*H_*W_)  // 32400
#define MPAD  32512       // 127*256
#define NPOS  (B_*H_*WFK) // 8280
#define LAM   0.01f

typedef __attribute__((ext_vector_type(8))) short short8;
typedef __attribute__((ext_vector_type(4))) float f32x4;

__device__ __forceinline__ float bf2f(short u) {
    union { unsigned int i; float f; } z;
    z.i = ((unsigned int)(unsigned short)u) << 16;
    return z.f;
}
__device__ __forceinline__ short f2b(float f) {
    return (short)__bfloat16_as_ushort(__float2bfloat16(f));
}

__device__ __forceinline__ void gload_lds16(const void* g, void* l) {
    __builtin_amdgcn_global_load_lds((const __attribute__((address_space(1))) void*)g,
                                     (__attribute__((address_space(3))) void*)l, 16, 0, 0);
}

// branch-free tanh-form GELU (max abs err ~1e-3, << bf16 rounding here)
__device__ __forceinline__ float gelu_f(float v) {
    float u = v * (0.7978845608028654f + 0.03567740813636141f * v * v);
    float au = fabsf(u);
    float e = __expf(2.f * au);
    float t = 1.f - 2.f / (e + 1.f);
    t = copysignf(t, u);
    return 0.5f * v * (1.f + t);
}

// ---------------- bf16 twiddle tables for all MFMA DFT stages ----------------
__global__ __launch_bounds__(256) void init_tables_kernel(__hip_bfloat16* Tw, __hip_bfloat16* Twf,
                                                          __hip_bfloat16* Thf, __hip_bfloat16* Thi) {
    int i = blockIdx.x * 256 + threadIdx.x;
    const float S = 0.00785674201318386f; // 1/sqrt(90*180)
    if (i < 192 * 96) {
        int w = i / 96, k = i % 96;
        int j = k >> 1, odd = k & 1;
        float val = 0.f;
        if (w < W_ && j < WFK) {
            float th = (float)((w * j) % W_) * (float)(6.283185307179586476925286766559 / 180.0);
            if (odd) val = (j == 0) ? 0.f : -2.f * S * sinf(th);
            else     val = (j == 0) ? S : 2.f * S * cosf(th);
        }
        Tw[i] = __float2bfloat16(val);
    }
    if (i < 96 * 192) {
        int r = i / 192, w = i % 192;
        int wf = r >> 1, odd = r & 1;
        float val = 0.f;
        if (w < W_ && wf < WFK) {
            float th = (float)((w * wf) % W_) * (float)(6.283185307179586476925286766559 / 180.0);
            val = odd ? -S * sinf(th) : S * cosf(th);
        }
        Twf[i] = __float2bfloat16(val);
    }
    if (i < 192 * 192) {
        int r = i / 192, j = i % 192;
        float vf = 0.f, vi = 0.f;
        if (r < 180 && j < 180) {
            int k = r >> 1, ro = r & 1, h = j >> 1, jo = j & 1;
            float th = (float)((k * h) % H_) * (float)(6.283185307179586476925286766559 / 90.0);
            float c = cosf(th), s = sinf(th);
            vf = ro ? (jo ? c : -s) : (jo ? s : c);   // fwd
            vi = ro ? (jo ? c : s) : (jo ? -s : c);   // inv
        }
        Thf[i] = __float2bfloat16(vf);
        Thi[i] = __float2bfloat16(vi);
    }
}

// ---------------- build expanded real weights for the block-MLP ----------------
__global__ __launch_bounds__(256) void wprep_kernel(
        const float* __restrict__ w1, const float* __restrict__ b1,
        const float* __restrict__ w2, const float* __restrict__ b2,
        __hip_bfloat16* __restrict__ wbig, float* __restrict__ bbig)
{
    int idx = blockIdx.x * 256 + threadIdx.x;
    if (idx < 2 * NBK * 192 * 192) {
        int k = idx % 192;
        int o = (idx / 192) % 192;
        int nb = (idx / (192 * 192)) % NBK;
        int L = idx / (192 * 192 * NBK);
        const float* w = L ? w2 : w1;
        const float* wr = w + (size_t)nb * BSK * BSK;
        const float* wi = w + (size_t)(NBK + nb) * BSK * BSK;
        int kk = k % BSK, oo = o % BSK;
        float val;
        if (o < BSK)  val = (k < BSK) ? wr[kk * BSK + oo] : -wi[kk * BSK + oo];
        else          val = (k < BSK) ? wi[kk * BSK + oo] :  wr[kk * BSK + oo];
        wbig[((size_t)(L * NBK + nb) * 192 + o) * 192 + k] = __float2bfloat16(val);
    }
    if (idx < 2 * NBK * 192) {
        int o = idx % 192;
        int nb = (idx / 192) % NBK;
        int L = idx / (192 * NBK);
        const float* b = L ? b2 : b1;
        bbig[idx] = (o < BSK) ? b[nb * BSK + o] : b[(NBK + nb) * BSK + (o - BSK)];
    }
}

// ---------------- LayerNorm: f32 in -> bf16 out, zero-pads rows >= ntok_valid ----------------
__global__ __launch_bounds__(256) void ln_kernel(const float* __restrict__ in,
        const float* __restrict__ w, const float* __restrict__ b,
        __hip_bfloat16* __restrict__ outb, int ntok_valid)
{
    int tok = blockIdx.x;
    int tid = threadIdx.x;
    size_t base = (size_t)tok * C_;
    if (tok >= ntok_valid) {
        __hip_bfloat16 z = __float2bfloat16(0.f);
        outb[base + tid] = z; outb[base + tid + 256] = z; outb[base + tid + 512] = z;
        return;
    }
    float x0 = in[base + tid], x1 = in[base + tid + 256], x2 = in[base + tid + 512];
    float s = x0 + x1 + x2;
    float q = x0*x0 + x1*x1 + x2*x2;
#pragma unroll
    for (int off = 32; off > 0; off >>= 1) { s += __shfl_down(s, off); q += __shfl_down(q, off); }
    __shared__ float rs[4], rq[4];
    int wid = tid >> 6, lane = tid & 63;
    if (lane == 0) { rs[wid] = s; rq[wid] = q; }
    __syncthreads();
    float ts = rs[0] + rs[1] + rs[2] + rs[3];
    float tq = rq[0] + rq[1] + rq[2] + rq[3];
    float mu = ts * (1.f / C_);
    float var = tq * (1.f / C_) - mu * mu;
    float rstd = rsqrtf(var + 1e-5f);
#pragma unroll
    for (int k = 0; k < 3; ++k) {
        int c = tid + k * 256;
        float xv = (k == 0 ? x0 : (k == 1 ? x1 : x2));
        outb[base + c] = __float2bfloat16((xv - mu) * rstd * w[c] + b[c]);
    }
}

// ---------------- forward rfft along W via MFMA: OUT[96][64] = Twf @ Xt^T (bf16 out) ----------------
__global__ __launch_bounds__(256) void wfft_kernel(const __hip_bfloat16* __restrict__ h1,
        short* __restrict__ f1r, short* __restrict__ f1i,
        const __hip_bfloat16* __restrict__ Twf)
{
    __shared__ __hip_bfloat16 Xt[64 * 200];  // [c][w], w pad 180..191 = 0
    int slab = blockIdx.x;           // b*90+h
    int c0 = blockIdx.y * 64;
    int tid = threadIdx.x, wid = tid >> 6, lane = tid & 63;
    int lrow = lane & 15, lk8 = lane >> 4;
    const short* src = (const short*)h1 + (size_t)slab * W_ * C_ + c0;
    short* X = (short*)Xt;
    for (int i = tid; i < W_ * 8; i += 256) {
        int w = i >> 3, c8 = (i & 7) * 8;
        short8 v = *(const short8*)&src[(size_t)w * C_ + c8];
#pragma unroll
        for (int j = 0; j < 8; ++j) X[(c8 + j) * 200 + w] = v[j];
    }
    for (int z = tid; z < 64 * 12; z += 256) {
        int c = z / 12, w = 180 + z % 12;
        Xt[c * 200 + w] = __float2bfloat16(0.f);
    }
    __syncthreads();
    const short* Tp = (const short*)Twf;
    f32x4 zero = {0.f, 0.f, 0.f, 0.f};
    f32x4 acc[6];
#pragma unroll
    for (int m = 0; m < 6; ++m) acc[m] = zero;
#pragma unroll
    for (int ks = 0; ks < 6; ++ks) {
        short8 bf = *(const short8*)&X[(wid * 16 + lrow) * 200 + ks * 32 + lk8 * 8];
#pragma unroll
        for (int m = 0; m < 6; ++m) {
            short8 af = *(const short8*)&Tp[(m * 16 + lrow) * 192 + ks * 32 + lk8 * 8];
            acc[m] = __builtin_amdgcn_mfma_f32_16x16x32_bf16(af, bf, acc[m], 0, 0, 0);
        }
    }
    int crow = (lane >> 4) * 4, ccol = lane & 15;
#pragma unroll
    for (int m = 0; m < 6; ++m)
#pragma unroll
        for (int j = 0; j < 4; ++j) {
            int r = m * 16 + crow + j;
            int wf = r >> 1;
            if (wf >= WFK) continue;
            size_t o = ((size_t)slab * WFK + wf) * C_ + c0 + wid * 16 + ccol;
            if (r & 1) f1i[o] = f2b(acc[m][j]);
            else       f1r[o] = f2b(acc[m][j]);
        }
}

// ---------------- complex DFT along H via MFMA, IN-PLACE (bf16 in/out): OUT[192][64] = Th @ Xt^T ----------------
__global__ __launch_bounds__(256) void hdft_kernel(short* __restrict__ dr, short* __restrict__ di,
        const __hip_bfloat16* __restrict__ Th)
{
    __shared__ __hip_bfloat16 Xt[64 * 200];  // [c][j], j=2h re / 2h+1 im, pad 180..191 = 0
    int bwf = blockIdx.x;            // b*46+wf
    int b = bwf / WFK, wf = bwf % WFK;
    int c0 = blockIdx.y * 64;
    int tid = threadIdx.x, wid = tid >> 6, lane = tid & 63;
    int lrow = lane & 15, lk8 = lane >> 4;
    size_t base = ((size_t)(b * H_) * WFK + wf) * C_ + c0;
    short* X = (short*)Xt;
    for (int i = tid; i < H_ * 8; i += 256) {
        int h = i >> 3, c8 = (i & 7) * 8;
        size_t a = base + (size_t)h * WFK * C_ + c8;
        short8 re = *(const short8*)&dr[a];
        short8 im = *(const short8*)&di[a];
#pragma unroll
        for (int j = 0; j < 8; ++j) {
            X[(c8 + j) * 200 + 2 * h]     = re[j];
            X[(c8 + j) * 200 + 2 * h + 1] = im[j];
        }
    }
    for (int z = tid; z < 64 * 12; z += 256) {
        int c = z / 12, j = 180 + z % 12;
        Xt[c * 200 + j] = __float2bfloat16(0.f);
    }
    __syncthreads();
    const short* Tp = (const short*)Th;
    f32x4 zero = {0.f, 0.f, 0.f, 0.f};
    f32x4 acc[3][4];
#pragma unroll
    for (int m = 0; m < 3; ++m)
#pragma unroll
        for (int n = 0; n < 4; ++n) acc[m][n] = zero;
#pragma unroll
    for (int ks = 0; ks < 6; ++ks) {
        short8 af[3], bf[4];
#pragma unroll
        for (int m = 0; m < 3; ++m)
            af[m] = *(const short8*)&Tp[(wid * 48 + m * 16 + lrow) * 192 + ks * 32 + lk8 * 8];
#pragma unroll
        for (int n = 0; n < 4; ++n)
            bf[n] = *(const short8*)&X[(n * 16 + lrow) * 200 + ks * 32 + lk8 * 8];
#pragma unroll
        for (int m = 0; m < 3; ++m)
#pragma unroll
            for (int n = 0; n < 4; ++n)
                acc[m][n] = __builtin_amdgcn_mfma_f32_16x16x32_bf16(af[m], bf[n], acc[m][n], 0, 0, 0);
    }
    int crow = (lane >> 4) * 4, ccol = lane & 15;
#pragma unroll
    for (int m = 0; m < 3; ++m)
#pragma unroll
        for (int j = 0; j < 4; ++j) {
            int r = wid * 48 + m * 16 + crow + j;
            int kh = r >> 1;
            if (kh >= H_) continue;
#pragma unroll
            for (int n = 0; n < 4; ++n) {
                size_t o = base + (size_t)kh * WFK * C_ + n * 16 + ccol;
                if (r & 1) di[o] = f2b(acc[m][n][j]);
                else       dr[o] = f2b(acc[m][n][j]);
            }
        }
}

// ---------------- block-diagonal complex 2-layer MLP + softshrink, IN-PLACE (bf16), via MFMA ----------------
__global__ __launch_bounds__(256) void blockmlp_mfma_kernel(
        short* __restrict__ vr, short* __restrict__ vi,
        const __hip_bfloat16* __restrict__ wbig, const float* __restrict__ bbig)
{
    __shared__ __hip_bfloat16 X1[64 * 200];
    __shared__ __hip_bfloat16 X2[64 * 200];
    int chunk = blockIdx.x;          // 130 chunks of 64 positions
    int nb = blockIdx.y;
    int tid = threadIdx.x, wid = tid >> 6, lane = tid & 63;
    int p0 = chunk * 64;
    short8 z8 = {0, 0, 0, 0, 0, 0, 0, 0};
    for (int i = tid; i < 64 * 24; i += 256) {
        int p = i / 24, q = i % 24;
        int pg = p0 + p;
        bool isr = q < 12;
        int c8 = (q % 12) * 8;
        short8 v = z8;
        if (pg < NPOS) {
            const short* src = isr ? vr : vi;
            v = *(const short8*)&src[(size_t)pg * C_ + nb * BSK + c8];
        }
        short* d = (short*)&X1[p * 200 + (isr ? 0 : 96) + c8];
#pragma unroll
        for (int j = 0; j < 8; ++j) d[j] = v[j];
    }
    __syncthreads();
    int n0 = wid * 48;
    int lrow = lane & 15, lk8 = lane >> 4;
    int crow = (lane >> 4) * 4, ccol = lane & 15;
    const short* W1 = (const short*)(wbig + (size_t)nb * 192 * 192);
    const short* W2 = (const short*)(wbig + (size_t)(NBK + nb) * 192 * 192);
    const float* bb1 = bbig + nb * 192;
    const float* bb2 = bbig + (NBK + nb) * 192;
    f32x4 zero = {0.f, 0.f, 0.f, 0.f};
    {
        f32x4 acc[4][3];
#pragma unroll
        for (int m = 0; m < 4; ++m)
#pragma unroll
            for (int n = 0; n < 3; ++n) acc[m][n] = zero;
#pragma unroll
        for (int k0 = 0; k0 < 192; k0 += 32) {
            short8 af[4], bf[3];
#pragma unroll
            for (int m = 0; m < 4; ++m)
                af[m] = *(const short8*)&X1[(m * 16 + lrow) * 200 + k0 + lk8 * 8];
#pragma unroll
            for (int n = 0; n < 3; ++n)
                bf[n] = *(const short8*)&W1[(size_t)(n0 + n * 16 + lrow) * 192 + k0 + lk8 * 8];
#pragma unroll
            for (int m = 0; m < 4; ++m)
#pragma unroll
                for (int n = 0; n < 3; ++n)
                    acc[m][n] = __builtin_amdgcn_mfma_f32_16x16x32_bf16(af[m], bf[n], acc[m][n], 0, 0, 0);
        }
        __syncthreads();
#pragma unroll
        for (int m = 0; m < 4; ++m)
#pragma unroll
            for (int j = 0; j < 4; ++j) {
                int row = m * 16 + crow + j;
#pragma unroll
                for (int n = 0; n < 3; ++n) {
                    int col = n0 + n * 16 + ccol;
                    float v = acc[m][n][j] + bb1[col];
                    X2[row * 200 + col] = __float2bfloat16(fmaxf(v, 0.f));
                }
            }
    }
    __syncthreads();
    {
        f32x4 acc[4][3];
#pragma unroll
        for (int m = 0; m < 4; ++m)
#pragma unroll
            for (int n = 0; n < 3; ++n) acc[m][n] = zero;
#pragma unroll
        for (int k0 = 0; k0 < 192; k0 += 32) {
            short8 af[4], bf[3];
#pragma unroll
            for (int m = 0; m < 4; ++m)
                af[m] = *(const short8*)&X2[(m * 16 + lrow) * 200 + k0 + lk8 * 8];
#pragma unroll
            for (int n = 0; n < 3; ++n)
                bf[n] = *(const short8*)&W2[(size_t)(n0 + n * 16 + lrow) * 192 + k0 + lk8 * 8];
#pragma unroll
            for (int m = 0; m < 4; ++m)
#pragma unroll
                for (int n = 0; n < 3; ++n)
                    acc[m][n] = __builtin_amdgcn_mfma_f32_16x16x32_bf16(af[m], bf[n], acc[m][n], 0, 0, 0);
        }
#pragma unroll
        for (int m = 0; m < 4; ++m)
#pragma unroll
            for (int j = 0; j < 4; ++j) {
                int row = m * 16 + crow + j;
                int pg = p0 + row;
                if (pg >= NPOS) continue;
#pragma unroll
                for (int n = 0; n < 3; ++n) {
                    int col = n0 + n * 16 + ccol;
                    float v = acc[m][n][j] + bb2[col];
                    v = v > LAM ? v - LAM : (v < -LAM ? v + LAM : 0.f);
                    if (col < BSK) vr[(size_t)pg * C_ + nb * BSK + col] = f2b(v);
                    else           vi[(size_t)pg * C_ + nb * BSK + col - BSK] = f2b(v);
                }
            }
    }
}

// ---------------- inverse rfft along W via MFMA (bf16 in): OUT[180][64] = Tw @ Yt^T, + residuals ----------------
__global__ __launch_bounds__(256) void iwfft_kernel(
        const short* __restrict__ inr, const short* __restrict__ ini,
        const __hip_bfloat16* __restrict__ h1, const float* __restrict__ x,
        float* __restrict__ out, const __hip_bfloat16* __restrict__ Tw)
{
    __shared__ __hip_bfloat16 Yt[64 * 104];   // [channel][k], k: 2j=re,2j+1=im, pad 92..95
    int slab = blockIdx.x;        // 180
    int c0 = blockIdx.y * 64;     // 12 groups
    int tid = threadIdx.x, wid = tid >> 6, lane = tid & 63;
    int lrow = lane & 15, lk8 = lane >> 4;
    size_t sb = (size_t)slab * WFK * C_ + c0;
    short* Y = (short*)Yt;
    for (int i = tid; i < WFK * 8; i += 256) {
        int wf = i >> 3, c8 = (i & 7) * 8;
        size_t a = sb + (size_t)wf * C_ + c8;
        short8 re = *(const short8*)&inr[a];
        short8 im = *(const short8*)&ini[a];
#pragma unroll
        for (int j = 0; j < 8; ++j) {
            Y[(c8 + j) * 104 + 2 * wf]     = re[j];
            Y[(c8 + j) * 104 + 2 * wf + 1] = im[j];
        }
    }
    {
        int c = tid >> 2, kk = 92 + (tid & 3);
        Yt[c * 104 + kk] = __float2bfloat16(0.f);
    }
    __syncthreads();
    const short* Tp = (const short*)Tw;
    f32x4 zero = {0.f, 0.f, 0.f, 0.f};
    f32x4 acc[3][4];
#pragma unroll
    for (int m = 0; m < 3; ++m)
#pragma unroll
        for (int n = 0; n < 4; ++n) acc[m][n] = zero;
#pragma unroll
    for (int ks = 0; ks < 3; ++ks) {
        short8 af[3], bf[4];
#pragma unroll
        for (int m = 0; m < 3; ++m)
            af[m] = *(const short8*)&Tp[(wid * 48 + m * 16 + lrow) * 96 + ks * 32 + lk8 * 8];
#pragma unroll
        for (int n = 0; n < 4; ++n)
            bf[n] = *(const short8*)&Y[(n * 16 + lrow) * 104 + ks * 32 + lk8 * 8];
#pragma unroll
        for (int m = 0; m < 3; ++m)
#pragma unroll
            for (int n = 0; n < 4; ++n)
                acc[m][n] = __builtin_amdgcn_mfma_f32_16x16x32_bf16(af[m], bf[n], acc[m][n], 0, 0, 0);
    }
    int crow = (lane >> 4) * 4, ccol = lane & 15;
    const short* hp = (const short*)h1;
#pragma unroll
    for (int m = 0; m < 3; ++m)
#pragma unroll
        for (int j = 0; j < 4; ++j) {
            int w = wid * 48 + m * 16 + crow + j;
            if (w >= W_) continue;
            size_t o = ((size_t)slab * W_ + w) * C_ + c0;
#pragma unroll
            for (int n = 0; n < 4; ++n) {
                int col = n * 16 + ccol;
                out[o + col] = acc[m][n][j] + bf2f(hp[o + col]) + x[o + col];
            }
        }
}

// ---------------- transpose + f32->bf16 (weights) ----------------
__global__ __launch_bounds__(256) void transpose_cvt_kernel(const float* __restrict__ Wm,
        __hip_bfloat16* __restrict__ Wt, int R, int Ccol)
{
    __shared__ float tile[32][33];
    int c0 = blockIdx.x * 32, r0 = blockIdx.y * 32;
    int tid = threadIdx.x;
    int tc = tid & 31, tr = tid >> 5;
#pragma unroll
    for (int k = 0; k < 4; ++k)
        tile[tr + k * 8][tc] = Wm[(size_t)(r0 + tr + k * 8) * Ccol + c0 + tc];
    __syncthreads();
    int rr = tid & 31, cc = tid >> 5;
#pragma unroll
    for (int k = 0; k < 4; ++k)
        Wt[(size_t)(c0 + cc + k * 8) * R + r0 + rr] = __float2bfloat16(tile[rr][cc + k * 8]);
}

// ---------------- 256xBNx64 bf16 MFMA GEMM — m201 geometry, compiler-scheduled inner loop ----------------
// 8 waves (2M x 4N), per-wave 128 x BN/4 out, acc[8][BN/64]; B-frags register-cached per K-tile.
// LDS = 2 bufs x {A[256][64] (32KB) | B[BN][64]}, XOR-octet swizzle (lane-const lrow&7).
// ONE __syncthreads() per K-tile (vmcnt drain free; doubles as WAR fence). No asm pins.
// BN=256 for fc1 (grid 1524, 5.95 rounds); BN=128 for fc2 (grid 762, 2.98 rounds - tail fix).
template<int EPI, int BN>
__global__ __launch_bounds__(512, 1) void gemm_kernel(
        const short* __restrict__ A, const short* __restrict__ Bt,
        const float* __restrict__ bias,
        __hip_bfloat16* __restrict__ obf, float* __restrict__ of32,
        const float* __restrict__ res, int N, int K, int mvalid, int MT, int NT)
{
    constexpr int NF = BN / 64;                 // n-frags per wave (4 or 2)
    constexpr int BP = BN / 64;                 // B stage p-iterations
    constexpr int BUFB = 32768 + BN * 128;      // bytes per buffer
    __shared__ short lds[BUFB];                 // 2 buffers x BUFB bytes = BUFB shorts total
    // ---- XCD remap: round-robin dispatch -> contiguous chunk per XCD ----
    int nwg = MT * NT;
    int orig = blockIdx.x;
    int xcd = orig & 7, loc = orig >> 3;
    int q = nwg >> 3, rm = nwg & 7;
    int wg = (xcd < rm ? xcd * (q + 1) : rm * (q + 1) + (xcd - rm) * q) + loc;
    // ---- supertile remap (bijective incl. remainder) ----
    const int SUPER = 4;
    int per = SUPER * NT;
    int sidx = wg / per, offs = wg % per;
    int rows = MT - sidx * SUPER; if (rows > SUPER) rows = SUPER;
    int mt = sidx * SUPER + offs % rows;
    int nt = offs / rows;
    size_t m0 = (size_t)mt * 256, n0 = (size_t)nt * BN;

    int tid = threadIdx.x;
    int wid = tid >> 6, lane = tid & 63;
    int wm = wid >> 2, wn = wid & 3;              // 2M x 4N waves; per-wave 128 x BN/4
    int lrow = lane & 15, lk8 = lane >> 4, l7 = lrow & 7;

    int srow = tid >> 3;                          // 0..63
    int sobase = tid & 7;
    f32x4 zero = {0.f, 0.f, 0.f, 0.f};
    f32x4 acc[8][NF];
#pragma unroll
    for (int i = 0; i < 8; ++i)
#pragma unroll
        for (int j = 0; j < NF; ++j) acc[i][j] = zero;

    auto stage = [&](int buf, int kt) {
        char* Ld = (char*)lds + buf * BUFB + (size_t)tid * 16;
#pragma unroll
        for (int p = 0; p < 4; ++p) {
            int row = p * 64 + srow;
            int soct = sobase ^ (row & 7);
            gload_lds16(A + (m0 + row) * (size_t)K + kt * 64 + soct * 8, Ld + p * 8192);
        }
#pragma unroll
        for (int p = 0; p < BP; ++p) {
            int row = p * 64 + srow;
            int soct = sobase ^ (row & 7);
            gload_lds16(Bt + (n0 + row) * (size_t)K + kt * 64 + soct * 8, Ld + 32768 + p * 8192);
        }
    };

    // read byte offsets (within a buffer): row*128 + ((ks*4+lk8)^l7)*16
    int aoff0 = (wm * 128 + lrow) * 128 + ((lk8) ^ l7) * 16;                 // ks=0; + mf*2048
    int aoff1 = (wm * 128 + lrow) * 128 + ((4 + lk8) ^ l7) * 16;             // ks=1
    int boff0 = 32768 + (wn * (BN / 4) + lrow) * 128 + ((lk8) ^ l7) * 16;    // + nf*2048
    int boff1 = 32768 + (wn * (BN / 4) + lrow) * 128 + ((4 + lk8) ^ l7) * 16;

    int NK = K >> 6;                 // 12 (fc1) / 48 (fc2)
    stage(0, 0);
    for (int t = 0; t < NK; ++t) {
        int buf = t & 1;
        __syncthreads();             // vmcnt drain (free) + WAR fence for restaging buf^1
        if (t + 1 < NK) stage(buf ^ 1, t + 1);
        const char* L = (const char*)lds + buf * BUFB;
        short8 bfr[NF][2];
#pragma unroll
        for (int nf = 0; nf < NF; ++nf) {
            bfr[nf][0] = *(const short8*)(L + boff0 + nf * 2048);
            bfr[nf][1] = *(const short8*)(L + boff1 + nf * 2048);
        }
#pragma unroll
        for (int p = 0; p < 4; ++p) {
            short8 af[2][2];
#pragma unroll
            for (int mh = 0; mh < 2; ++mh) {
                af[mh][0] = *(const short8*)(L + aoff0 + (2 * p + mh) * 2048);
                af[mh][1] = *(const short8*)(L + aoff1 + (2 * p + mh) * 2048);
            }
#pragma unroll
            for (int mh = 0; mh < 2; ++mh)
#pragma unroll
                for (int nf = 0; nf < NF; ++nf) {
                    acc[2 * p + mh][nf] = __builtin_amdgcn_mfma_f32_16x16x32_bf16(
                        af[mh][0], bfr[nf][0], acc[2 * p + mh][nf], 0, 0, 0);
                    acc[2 * p + mh][nf] = __builtin_amdgcn_mfma_f32_16x16x32_bf16(
                        af[mh][1], bfr[nf][1], acc[2 * p + mh][nf], 0, 0, 0);
                }
        }
    }

    int crow = (lane >> 4) * 4;
    int ccol = lane & 15;
#pragma unroll
    for (int mf = 0; mf < 8; ++mf) {
#pragma unroll
        for (int j = 0; j < 4; ++j) {
            size_t r = m0 + wm * 128 + mf * 16 + crow + j;
            if (EPI == 1 && r >= (size_t)mvalid) continue;
#pragma unroll
            for (int nf = 0; nf < NF; ++nf) {
                size_t cidx = n0 + wn * (BN / 4) + nf * 16 + ccol;
                float v = acc[mf][nf][j] + bias[cidx];
                if (EPI == 0) {
                    obf[r * N + cidx] = __float2bfloat16(gelu_f(v));
                } else {
                    of32[r * N + cidx] = v + res[r * N + cidx];
                }
            }
        }
    }
}

extern "C" void kernel_launch(void* const* d_in, const int* in_sizes, int n_in,
                              void* d_out, int out_size, void* d_ws, size_t ws_size,
                              hipStream_t stream) {
    (void)in_sizes; (void)n_in; (void)out_size;
    const float* x    = (const float*)d_in[0];
    const float* n1w  = (const float*)d_in[1];
    const float* n1b  = (const float*)d_in[2];
    const float* w1   = (const float*)d_in[3];
    const float* b1   = (const float*)d_in[4];
    const float* w2   = (const float*)d_in[5];
    const float* b2   = (const float*)d_in[6];
    const float* n2w  = (const float*)d_in[7];
    const float* n2b  = (const float*)d_in[8];
    const float* fc1w = (const float*)d_in[9];
    const float* fc1b = (const float*)d_in[10];
    const float* fc2w = (const float*)d_in[11];
    const float* fc2b = (const float*)d_in[12];
    float* out = (float*)d_out;

    // ---- tiered chunking over 256-row m-tiles (127 total) ----
    const size_t fl_region1 = (size_t)MPAD * C_ / 2;            // h1/h3 bf16
    const size_t fl_f1      = (size_t)NPOS * C_;                // f1r+f1i bf16
    const size_t fl_tb1     = (size_t)MPAD * HID / 2;           // full-M tb bf16
    const size_t fl_tb2     = (size_t)64 * 256 * HID / 2;       // 64-tile chunk tb
    const size_t fl_wx      = 2712576 + 4096;
    const size_t need1 = (fl_region1 + fl_tb1 + fl_wx) * 4;
    const size_t need2 = (fl_region1 + ((fl_f1 > fl_tb2) ? fl_f1 : fl_tb2) + fl_wx) * 4;
    int nch = (ws_size >= need1) ? 1 : (ws_size >= need2) ? 2 : 4;
    size_t fl_tb = (nch == 1) ? fl_tb1 : (nch == 2) ? fl_tb2 : 0;
    size_t fl_big = (fl_f1 > fl_tb) ? fl_f1 : fl_tb;

    float* wsf = (float*)d_ws;
    size_t off = 0;
    auto alloc = [&](size_t nfloats) { float* p = wsf + off; off += (nfloats + 63) & ~(size_t)63; return p; };
    float* region1   = alloc(fl_region1);     // h1 (bf16) then h3 (bf16)
    float* regionBig = alloc(fl_big);         // f1r,f1i (bf16) then tb (bf16 chunk)
    __hip_bfloat16* w1t = (__hip_bfloat16*)alloc((size_t)HID * C_ / 2);
    __hip_bfloat16* w2t = (__hip_bfloat16*)alloc((size_t)HID * C_ / 2);
    __hip_bfloat16* wbig = (__hip_bfloat16*)alloc((size_t)2 * NBK * 192 * 192 / 2);
    float* bbig = alloc(2 * NBK * 192);
    __hip_bfloat16* Tw  = (__hip_bfloat16*)alloc(192 * 96 / 2);
    __hip_bfloat16* Twf = (__hip_bfloat16*)alloc(96 * 192 / 2);
    __hip_bfloat16* Thf = (__hip_bfloat16*)alloc(192 * 192 / 2);
    __hip_bfloat16* Thi = (__hip_bfloat16*)alloc(192 * 192 / 2);

    __hip_bfloat16* h1b = (__hip_bfloat16*)region1;
    __hip_bfloat16* h3  = (__hip_bfloat16*)region1;
    short* f1r = (short*)regionBig;
    short* f1i = f1r + (size_t)NPOS * C_;
    __hip_bfloat16* tb  = (__hip_bfloat16*)regionBig;

    init_tables_kernel<<<144, 256, 0, stream>>>(Tw, Twf, Thf, Thi);
    wprep_kernel<<<(2 * NBK * 192 * 192 + 255) / 256, 256, 0, stream>>>(w1, b1, w2, b2, wbig, bbig);
    transpose_cvt_kernel<<<dim3(HID / 32, C_ / 32), 256, 0, stream>>>(fc1w, w1t, C_, HID);
    transpose_cvt_kernel<<<dim3(C_ / 32, HID / 32), 256, 0, stream>>>(fc2w, w2t, HID, C_);

    ln_kernel<<<NTOK, 256, 0, stream>>>(x, n1w, n1b, h1b, NTOK);
    wfft_kernel<<<dim3(B_ * H_, 12), 256, 0, stream>>>(h1b, f1r, f1i, Twf);
    hdft_kernel<<<dim3(B_ * WFK, 12), 256, 0, stream>>>(f1r, f1i, Thf);
    blockmlp_mfma_kernel<<<dim3(130, NBK), 256, 0, stream>>>(f1r, f1i, wbig, bbig);
    hdft_kernel<<<dim3(B_ * WFK, 12), 256, 0, stream>>>(f1r, f1i, Thi);
    iwfft_kernel<<<dim3(B_ * H_, 12), 256, 0, stream>>>(f1r, f1i, h1b, x, out, Tw);
    // h1b, f1r/f1i dead from here; regions reused by h3 and tb
    ln_kernel<<<MPAD, 256, 0, stream>>>(out, n2w, n2b, h3, NTOK);

    int tilesArr[4], ntiles = 0;
    if (nch == 1)      { tilesArr[0] = 127; ntiles = 1; }
    else if (nch == 2) { tilesArr[0] = 64; tilesArr[1] = 63; ntiles = 2; }
    else               { tilesArr[0] = 32; tilesArr[1] = 32; tilesArr[2] = 32; tilesArr[3] = 31; ntiles = 4; }
    int baseT = 0;
    for (int c = 0; c < ntiles; ++c) {
        int tiles = tilesArr[c];
        size_t baseRow = (size_t)baseT * 256;
        gemm_kernel<0, 256><<<tiles * (HID / 256), 512, 0, stream>>>(
            (const short*)(h3 + baseRow * C_), (const short*)w1t, fc1b,
            tb, nullptr, nullptr, HID, C_, 0, tiles, HID / 256);
        gemm_kernel<1, 128><<<tiles * (C_ / 128), 512, 0, stream>>>(
            (const short*)tb, (const short*)w2t, fc2b,
            nullptr, out + baseRow * C_, out + baseRow * C_, C_, HID, NTOK - (int)baseRow, tiles, C_ / 128);
        baseT += tiles;
    }
}

// Round 19
// 694.485 us; speedup vs baseline: 1.0688x; 1.0688x over previous
//
#include <hip/hip_runtime.h>
#include <hip/hip_bf16.h>

#define B_    2
#define H_    90
#define W_    180
#define C_    768
#define WFK   46          // kept W-frequency modes (of 91)
#define NBK   8
#define BSK   96
#define HID   3072
#define NTOK  (B_*H_*W_)  // 32400
#define MPAD  32512       // 127*256
#define NPOS  (B_*H_*WFK) // 8280
#define LAM   0.01f

typedef __attribute__((ext_vector_type(8))) short short8;
typedef __attribute__((ext_vector_type(4))) float f32x4;

__device__ __forceinline__ float bf2f(short u) {
    union { unsigned int i; float f; } z;
    z.i = ((unsigned int)(unsigned short)u) << 16;
    return z.f;
}
__device__ __forceinline__ short f2b(float f) {
    return (short)__bfloat16_as_ushort(__float2bfloat16(f));
}

__device__ __forceinline__ void gload_lds16(const void* g, void* l) {
    __builtin_amdgcn_global_load_lds((const __attribute__((address_space(1))) void*)g,
                                     (__attribute__((address_space(3))) void*)l, 16, 0, 0);
}

// branch-free tanh-form GELU (max abs err ~1e-3, << bf16 rounding here)
__device__ __forceinline__ float gelu_f(float v) {
    float u = v * (0.7978845608028654f + 0.03567740813636141f * v * v);
    float au = fabsf(u);
    float e = __expf(2.f * au);
    float t = 1.f - 2.f / (e + 1.f);
    t = copysignf(t, u);
    return 0.5f * v * (1.f + t);
}

// ---------------- bf16 twiddle tables for all MFMA DFT stages ----------------
__global__ __launch_bounds__(256) void init_tables_kernel(__hip_bfloat16* Tw, __hip_bfloat16* Twf,
                                                          __hip_bfloat16* Thf, __hip_bfloat16* Thi) {
    int i = blockIdx.x * 256 + threadIdx.x;
    const float S = 0.00785674201318386f; // 1/sqrt(90*180)
    if (i < 192 * 96) {
        int w = i / 96, k = i % 96;
        int j = k >> 1, odd = k & 1;
        float val = 0.f;
        if (w < W_ && j < WFK) {
            float th = (float)((w * j) % W_) * (float)(6.283185307179586476925286766559 / 180.0);
            if (odd) val = (j == 0) ? 0.f : -2.f * S * sinf(th);
            else     val = (j == 0) ? S : 2.f * S * cosf(th);
        }
        Tw[i] = __float2bfloat16(val);
    }
    if (i < 96 * 192) {
        int r = i / 192, w = i % 192;
        int wf = r >> 1, odd = r & 1;
        float val = 0.f;
        if (w < W_ && wf < WFK) {
            float th = (float)((w * wf) % W_) * (float)(6.283185307179586476925286766559 / 180.0);
            val = odd ? -S * sinf(th) : S * cosf(th);
        }
        Twf[i] = __float2bfloat16(val);
    }
    if (i < 192 * 192) {
        int r = i / 192, j = i % 192;
        float vf = 0.f, vi = 0.f;
        if (r < 180 && j < 180) {
            int k = r >> 1, ro = r & 1, h = j >> 1, jo = j & 1;
            float th = (float)((k * h) % H_) * (float)(6.283185307179586476925286766559 / 90.0);
            float c = cosf(th), s = sinf(th);
            vf = ro ? (jo ? c : -s) : (jo ? s : c);   // fwd
            vi = ro ? (jo ? c : s) : (jo ? -s : c);   // inv
        }
        Thf[i] = __float2bfloat16(vf);
        Thi[i] = __float2bfloat16(vi);
    }
}

// ---------------- build expanded real weights for the block-MLP ----------------
__global__ __launch_bounds__(256) void wprep_kernel(
        const float* __restrict__ w1, const float* __restrict__ b1,
        const float* __restrict__ w2, const float* __restrict__ b2,
        __hip_bfloat16* __restrict__ wbig, float* __restrict__ bbig)
{
    int idx = blockIdx.x * 256 + threadIdx.x;
    if (idx < 2 * NBK * 192 * 192) {
        int k = idx % 192;
        int o = (idx / 192) % 192;
        int nb = (idx / (192 * 192)) % NBK;
        int L = idx / (192 * 192 * NBK);
        const float* w = L ? w2 : w1;
        const float* wr = w + (size_t)nb * BSK * BSK;
        const float* wi = w + (size_t)(NBK + nb) * BSK * BSK;
        int kk = k % BSK, oo = o % BSK;
        float val;
        if (o < BSK)  val = (k < BSK) ? wr[kk * BSK + oo] : -wi[kk * BSK + oo];
        else          val = (k < BSK) ? wi[kk * BSK + oo] :  wr[kk * BSK + oo];
        wbig[((size_t)(L * NBK + nb) * 192 + o) * 192 + k] = __float2bfloat16(val);
    }
    if (idx < 2 * NBK * 192) {
        int o = idx % 192;
        int nb = (idx / 192) % NBK;
        int L = idx / (192 * NBK);
        const float* b = L ? b2 : b1;
        bbig[idx] = (o < BSK) ? b[nb * BSK + o] : b[(NBK + nb) * BSK + (o - BSK)];
    }
}

// ---------------- LayerNorm: f32 in -> bf16 out, zero-pads rows >= ntok_valid ----------------
__global__ __launch_bounds__(256) void ln_kernel(const float* __restrict__ in,
        const float* __restrict__ w, const float* __restrict__ b,
        __hip_bfloat16* __restrict__ outb, int ntok_valid)
{
    int tok = blockIdx.x;
    int tid = threadIdx.x;
    size_t base = (size_t)tok * C_;
    if (tok >= ntok_valid) {
        __hip_bfloat16 z = __float2bfloat16(0.f);
        outb[base + tid] = z; outb[base + tid + 256] = z; outb[base + tid + 512] = z;
        return;
    }
    float x0 = in[base + tid], x1 = in[base + tid + 256], x2 = in[base + tid + 512];
    float s = x0 + x1 + x2;
    float q = x0*x0 + x1*x1 + x2*x2;
#pragma unroll
    for (int off = 32; off > 0; off >>= 1) { s += __shfl_down(s, off); q += __shfl_down(q, off); }
    __shared__ float rs[4], rq[4];
    int wid = tid >> 6, lane = tid & 63;
    if (lane == 0) { rs[wid] = s; rq[wid] = q; }
    __syncthreads();
    float ts = rs[0] + rs[1] + rs[2] + rs[3];
    float tq = rq[0] + rq[1] + rq[2] + rq[3];
    float mu = ts * (1.f / C_);
    float var = tq * (1.f / C_) - mu * mu;
    float rstd = rsqrtf(var + 1e-5f);
#pragma unroll
    for (int k = 0; k < 3; ++k) {
        int c = tid + k * 256;
        float xv = (k == 0 ? x0 : (k == 1 ? x1 : x2));
        outb[base + c] = __float2bfloat16((xv - mu) * rstd * w[c] + b[c]);
    }
}

// ---------------- forward rfft along W via MFMA: OUT[96][64] = Twf @ Xt^T (bf16 out) ----------------
__global__ __launch_bounds__(256) void wfft_kernel(const __hip_bfloat16* __restrict__ h1,
        short* __restrict__ f1r, short* __restrict__ f1i,
        const __hip_bfloat16* __restrict__ Twf)
{
    __shared__ __hip_bfloat16 Xt[64 * 200];  // [c][w], w pad 180..191 = 0
    int slab = blockIdx.x;           // b*90+h
    int c0 = blockIdx.y * 64;
    int tid = threadIdx.x, wid = tid >> 6, lane = tid & 63;
    int lrow = lane & 15, lk8 = lane >> 4;
    const short* src = (const short*)h1 + (size_t)slab * W_ * C_ + c0;
    short* X = (short*)Xt;
    for (int i = tid; i < W_ * 8; i += 256) {
        int w = i >> 3, c8 = (i & 7) * 8;
        short8 v = *(const short8*)&src[(size_t)w * C_ + c8];
#pragma unroll
        for (int j = 0; j < 8; ++j) X[(c8 + j) * 200 + w] = v[j];
    }
    for (int z = tid; z < 64 * 12; z += 256) {
        int c = z / 12, w = 180 + z % 12;
        Xt[c * 200 + w] = __float2bfloat16(0.f);
    }
    __syncthreads();
    const short* Tp = (const short*)Twf;
    f32x4 zero = {0.f, 0.f, 0.f, 0.f};
    f32x4 acc[6];
#pragma unroll
    for (int m = 0; m < 6; ++m) acc[m] = zero;
#pragma unroll
    for (int ks = 0; ks < 6; ++ks) {
        short8 bf = *(const short8*)&X[(wid * 16 + lrow) * 200 + ks * 32 + lk8 * 8];
#pragma unroll
        for (int m = 0; m < 6; ++m) {
            short8 af = *(const short8*)&Tp[(m * 16 + lrow) * 192 + ks * 32 + lk8 * 8];
            acc[m] = __builtin_amdgcn_mfma_f32_16x16x32_bf16(af, bf, acc[m], 0, 0, 0);
        }
    }
    int crow = (lane >> 4) * 4, ccol = lane & 15;
#pragma unroll
    for (int m = 0; m < 6; ++m)
#pragma unroll
        for (int j = 0; j < 4; ++j) {
            int r = m * 16 + crow + j;
            int wf = r >> 1;
            if (wf >= WFK) continue;
            size_t o = ((size_t)slab * WFK + wf) * C_ + c0 + wid * 16 + ccol;
            if (r & 1) f1i[o] = f2b(acc[m][j]);
            else       f1r[o] = f2b(acc[m][j]);
        }
}

// ---------------- complex DFT along H via MFMA, IN-PLACE (bf16 in/out): OUT[192][64] = Th @ Xt^T ----------------
__global__ __launch_bounds__(256) void hdft_kernel(short* __restrict__ dr, short* __restrict__ di,
        const __hip_bfloat16* __restrict__ Th)
{
    __shared__ __hip_bfloat16 Xt[64 * 200];  // [c][j], j=2h re / 2h+1 im, pad 180..191 = 0
    int bwf = blockIdx.x;            // b*46+wf
    int b = bwf / WFK, wf = bwf % WFK;
    int c0 = blockIdx.y * 64;
    int tid = threadIdx.x, wid = tid >> 6, lane = tid & 63;
    int lrow = lane & 15, lk8 = lane >> 4;
    size_t base = ((size_t)(b * H_) * WFK + wf) * C_ + c0;
    short* X = (short*)Xt;
    for (int i = tid; i < H_ * 8; i += 256) {
        int h = i >> 3, c8 = (i & 7) * 8;
        size_t a = base + (size_t)h * WFK * C_ + c8;
        short8 re = *(const short8*)&dr[a];
        short8 im = *(const short8*)&di[a];
#pragma unroll
        for (int j = 0; j < 8; ++j) {
            X[(c8 + j) * 200 + 2 * h]     = re[j];
            X[(c8 + j) * 200 + 2 * h + 1] = im[j];
        }
    }
    for (int z = tid; z < 64 * 12; z += 256) {
        int c = z / 12, j = 180 + z % 12;
        Xt[c * 200 + j] = __float2bfloat16(0.f);
    }
    __syncthreads();
    const short* Tp = (const short*)Th;
    f32x4 zero = {0.f, 0.f, 0.f, 0.f};
    f32x4 acc[3][4];
#pragma unroll
    for (int m = 0; m < 3; ++m)
#pragma unroll
        for (int n = 0; n < 4; ++n) acc[m][n] = zero;
#pragma unroll
    for (int ks = 0; ks < 6; ++ks) {
        short8 af[3], bf[4];
#pragma unroll
        for (int m = 0; m < 3; ++m)
            af[m] = *(const short8*)&Tp[(wid * 48 + m * 16 + lrow) * 192 + ks * 32 + lk8 * 8];
#pragma unroll
        for (int n = 0; n < 4; ++n)
            bf[n] = *(const short8*)&X[(n * 16 + lrow) * 200 + ks * 32 + lk8 * 8];
#pragma unroll
        for (int m = 0; m < 3; ++m)
#pragma unroll
            for (int n = 0; n < 4; ++n)
                acc[m][n] = __builtin_amdgcn_mfma_f32_16x16x32_bf16(af[m], bf[n], acc[m][n], 0, 0, 0);
    }
    int crow = (lane >> 4) * 4, ccol = lane & 15;
#pragma unroll
    for (int m = 0; m < 3; ++m)
#pragma unroll
        for (int j = 0; j < 4; ++j) {
            int r = wid * 48 + m * 16 + crow + j;
            int kh = r >> 1;
            if (kh >= H_) continue;
#pragma unroll
            for (int n = 0; n < 4; ++n) {
                size_t o = base + (size_t)kh * WFK * C_ + n * 16 + ccol;
                if (r & 1) di[o] = f2b(acc[m][n][j]);
                else       dr[o] = f2b(acc[m][n][j]);
            }
        }
}

// ---------------- block-diagonal complex 2-layer MLP + softshrink, IN-PLACE (bf16), via MFMA ----------------
__global__ __launch_bounds__(256) void blockmlp_mfma_kernel(
        short* __restrict__ vr, short* __restrict__ vi,
        const __hip_bfloat16* __restrict__ wbig, const float* __restrict__ bbig)
{
    __shared__ __hip_bfloat16 X1[64 * 200];
    __shared__ __hip_bfloat16 X2[64 * 200];
    int chunk = blockIdx.x;          // 130 chunks of 64 positions
    int nb = blockIdx.y;
    int tid = threadIdx.x, wid = tid >> 6, lane = tid & 63;
    int p0 = chunk * 64;
    short8 z8 = {0, 0, 0, 0, 0, 0, 0, 0};
    for (int i = tid; i < 64 * 24; i += 256) {
        int p = i / 24, q = i % 24;
        int pg = p0 + p;
        bool isr = q < 12;
        int c8 = (q % 12) * 8;
        short8 v = z8;
        if (pg < NPOS) {
            const short* src = isr ? vr : vi;
            v = *(const short8*)&src[(size_t)pg * C_ + nb * BSK + c8];
        }
        short* d = (short*)&X1[p * 200 + (isr ? 0 : 96) + c8];
#pragma unroll
        for (int j = 0; j < 8; ++j) d[j] = v[j];
    }
    __syncthreads();
    int n0 = wid * 48;
    int lrow = lane & 15, lk8 = lane >> 4;
    int crow = (lane >> 4) * 4, ccol = lane & 15;
    const short* W1 = (const short*)(wbig + (size_t)nb * 192 * 192);
    const short* W2 = (const short*)(wbig + (size_t)(NBK + nb) * 192 * 192);
    const float* bb1 = bbig + nb * 192;
    const float* bb2 = bbig + (NBK + nb) * 192;
    f32x4 zero = {0.f, 0.f, 0.f, 0.f};
    {
        f32x4 acc[4][3];
#pragma unroll
        for (int m = 0; m < 4; ++m)
#pragma unroll
            for (int n = 0; n < 3; ++n) acc[m][n] = zero;
#pragma unroll
        for (int k0 = 0; k0 < 192; k0 += 32) {
            short8 af[4], bf[3];
#pragma unroll
            for (int m = 0; m < 4; ++m)
                af[m] = *(const short8*)&X1[(m * 16 + lrow) * 200 + k0 + lk8 * 8];
#pragma unroll
            for (int n = 0; n < 3; ++n)
                bf[n] = *(const short8*)&W1[(size_t)(n0 + n * 16 + lrow) * 192 + k0 + lk8 * 8];
#pragma unroll
            for (int m = 0; m < 4; ++m)
#pragma unroll
                for (int n = 0; n < 3; ++n)
                    acc[m][n] = __builtin_amdgcn_mfma_f32_16x16x32_bf16(af[m], bf[n], acc[m][n], 0, 0, 0);
        }
        __syncthreads();
#pragma unroll
        for (int m = 0; m < 4; ++m)
#pragma unroll
            for (int j = 0; j < 4; ++j) {
                int row = m * 16 + crow + j;
#pragma unroll
                for (int n = 0; n < 3; ++n) {
                    int col = n0 + n * 16 + ccol;
                    float v = acc[m][n][j] + bb1[col];
                    X2[row * 200 + col] = __float2bfloat16(fmaxf(v, 0.f));
                }
            }
    }
    __syncthreads();
    {
        f32x4 acc[4][3];
#pragma unroll
        for (int m = 0; m < 4; ++m)
#pragma unroll
            for (int n = 0; n < 3; ++n) acc[m][n] = zero;
#pragma unroll
        for (int k0 = 0; k0 < 192; k0 += 32) {
            short8 af[4], bf[3];
#pragma unroll
            for (int m = 0; m < 4; ++m)
                af[m] = *(const short8*)&X2[(m * 16 + lrow) * 200 + k0 + lk8 * 8];
#pragma unroll
            for (int n = 0; n < 3; ++n)
                bf[n] = *(const short8*)&W2[(size_t)(n0 + n * 16 + lrow) * 192 + k0 + lk8 * 8];
#pragma unroll
            for (int m = 0; m < 4; ++m)
#pragma unroll
                for (int n = 0; n < 3; ++n)
                    acc[m][n] = __builtin_amdgcn_mfma_f32_16x16x32_bf16(af[m], bf[n], acc[m][n], 0, 0, 0);
        }
#pragma unroll
        for (int m = 0; m < 4; ++m)
#pragma unroll
            for (int j = 0; j < 4; ++j) {
                int row = m * 16 + crow + j;
                int pg = p0 + row;
                if (pg >= NPOS) continue;
#pragma unroll
                for (int n = 0; n < 3; ++n) {
                    int col = n0 + n * 16 + ccol;
                    float v = acc[m][n][j] + bb2[col];
                    v = v > LAM ? v - LAM : (v < -LAM ? v + LAM : 0.f);
                    if (col < BSK) vr[(size_t)pg * C_ + nb * BSK + col] = f2b(v);
                    else           vi[(size_t)pg * C_ + nb * BSK + col - BSK] = f2b(v);
                }
            }
    }
}

// ---------------- inverse rfft along W via MFMA (bf16 in): OUT[180][64] = Tw @ Yt^T, + residuals ----------------
__global__ __launch_bounds__(256) void iwfft_kernel(
        const short* __restrict__ inr, const short* __restrict__ ini,
        const __hip_bfloat16* __restrict__ h1, const float* __restrict__ x,
        float* __restrict__ out, const __hip_bfloat16* __restrict__ Tw)
{
    __shared__ __hip_bfloat16 Yt[64 * 104];   // [channel][k], k: 2j=re,2j+1=im, pad 92..95
    int slab = blockIdx.x;        // 180
    int c0 = blockIdx.y * 64;     // 12 groups
    int tid = threadIdx.x, wid = tid >> 6, lane = tid & 63;
    int lrow = lane & 15, lk8 = lane >> 4;
    size_t sb = (size_t)slab * WFK * C_ + c0;
    short* Y = (short*)Yt;
    for (int i = tid; i < WFK * 8; i += 256) {
        int wf = i >> 3, c8 = (i & 7) * 8;
        size_t a = sb + (size_t)wf * C_ + c8;
        short8 re = *(const short8*)&inr[a];
        short8 im = *(const short8*)&ini[a];
#pragma unroll
        for (int j = 0; j < 8; ++j) {
            Y[(c8 + j) * 104 + 2 * wf]     = re[j];
            Y[(c8 + j) * 104 + 2 * wf + 1] = im[j];
        }
    }
    {
        int c = tid >> 2, kk = 92 + (tid & 3);
        Yt[c * 104 + kk] = __float2bfloat16(0.f);
    }
    __syncthreads();
    const short* Tp = (const short*)Tw;
    f32x4 zero = {0.f, 0.f, 0.f, 0.f};
    f32x4 acc[3][4];
#pragma unroll
    for (int m = 0; m < 3; ++m)
#pragma unroll
        for (int n = 0; n < 4; ++n) acc[m][n] = zero;
#pragma unroll
    for (int ks = 0; ks < 3; ++ks) {
        short8 af[3], bf[4];
#pragma unroll
        for (int m = 0; m < 3; ++m)
            af[m] = *(const short8*)&Tp[(wid * 48 + m * 16 + lrow) * 96 + ks * 32 + lk8 * 8];
#pragma unroll
        for (int n = 0; n < 4; ++n)
            bf[n] = *(const short8*)&Y[(n * 16 + lrow) * 104 + ks * 32 + lk8 * 8];
#pragma unroll
        for (int m = 0; m < 3; ++m)
#pragma unroll
            for (int n = 0; n < 4; ++n)
                acc[m][n] = __builtin_amdgcn_mfma_f32_16x16x32_bf16(af[m], bf[n], acc[m][n], 0, 0, 0);
    }
    int crow = (lane >> 4) * 4, ccol = lane & 15;
    const short* hp = (const short*)h1;
#pragma unroll
    for (int m = 0; m < 3; ++m)
#pragma unroll
        for (int j = 0; j < 4; ++j) {
            int w = wid * 48 + m * 16 + crow + j;
            if (w >= W_) continue;
            size_t o = ((size_t)slab * W_ + w) * C_ + c0;
#pragma unroll
            for (int n = 0; n < 4; ++n) {
                int col = n * 16 + ccol;
                out[o + col] = acc[m][n][j] + bf2f(hp[o + col]) + x[o + col];
            }
        }
}

// ---------------- transpose + f32->bf16 (weights) ----------------
__global__ __launch_bounds__(256) void transpose_cvt_kernel(const float* __restrict__ Wm,
        __hip_bfloat16* __restrict__ Wt, int R, int Ccol)
{
    __shared__ float tile[32][33];
    int c0 = blockIdx.x * 32, r0 = blockIdx.y * 32;
    int tid = threadIdx.x;
    int tc = tid & 31, tr = tid >> 5;
#pragma unroll
    for (int k = 0; k < 4; ++k)
        tile[tr + k * 8][tc] = Wm[(size_t)(r0 + tr + k * 8) * Ccol + c0 + tc];
    __syncthreads();
    int rr = tid & 31, cc = tid >> 5;
#pragma unroll
    for (int k = 0; k < 4; ++k)
        Wt[(size_t)(c0 + cc + k * 8) * R + r0 + rr] = __float2bfloat16(tile[rr][cc + k * 8]);
}

// ---------------- BMxBNx64 bf16 MFMA GEMM — m201 geometry, compiler-scheduled inner loop ----------------
// 8 waves (2M x 4N), per-wave (BM/2) x (BN/4) out; B-frags register-cached per K-tile.
// LDS = 2 bufs x {A[BM][64] | B[BN][64]}, XOR-octet swizzle (lane-const lrow&7).
// ONE __syncthreads() per K-tile. fc1: BM=256,BN=256 (grid 6x rounds). fc2: BM=128,BN=256
// (grid 762 = 2.98 rounds — tail fix with NT unchanged so A-refetch stays flat).
template<int EPI, int BM, int BN>
__global__ __launch_bounds__(512, 1) void gemm_kernel(
        const short* __restrict__ A, const short* __restrict__ Bt,
        const float* __restrict__ bias,
        __hip_bfloat16* __restrict__ obf, float* __restrict__ of32,
        const float* __restrict__ res, int N, int K, int mvalid, int MT, int NT)
{
    constexpr int MF = BM / 32;                 // m-frags per wave (8 or 4)
    constexpr int NF = BN / 64;                 // n-frags per wave (4)
    constexpr int AP = BM / 64;                 // A stage iterations (4 or 2)
    constexpr int BP = BN / 64;                 // B stage iterations (4)
    constexpr int ABYTES = BM * 128;            // A region bytes per buffer
    constexpr int BUFB = ABYTES + BN * 128;     // bytes per buffer
    __shared__ short lds[BUFB];                 // 2 buffers (BUFB shorts = 2*BUFB bytes)
    // ---- XCD remap: round-robin dispatch -> contiguous chunk per XCD ----
    int nwg = MT * NT;
    int orig = blockIdx.x;
    int xcd = orig & 7, loc = orig >> 3;
    int q = nwg >> 3, rm = nwg & 7;
    int wg = (xcd < rm ? xcd * (q + 1) : rm * (q + 1) + (xcd - rm) * q) + loc;
    // ---- supertile remap (bijective incl. remainder) ----
    const int SUPER = 4;
    int per = SUPER * NT;
    int sidx = wg / per, offs = wg % per;
    int rows = MT - sidx * SUPER; if (rows > SUPER) rows = SUPER;
    int mt = sidx * SUPER + offs % rows;
    int nt = offs / rows;
    size_t m0 = (size_t)mt * BM, n0 = (size_t)nt * BN;

    int tid = threadIdx.x;
    int wid = tid >> 6, lane = tid & 63;
    int wm = wid >> 2, wn = wid & 3;              // 2M x 4N waves
    int lrow = lane & 15, lk8 = lane >> 4, l7 = lrow & 7;

    int srow = tid >> 3;                          // 0..63
    int sobase = tid & 7;
    f32x4 zero = {0.f, 0.f, 0.f, 0.f};
    f32x4 acc[MF][NF];
#pragma unroll
    for (int i = 0; i < MF; ++i)
#pragma unroll
        for (int j = 0; j < NF; ++j) acc[i][j] = zero;

    auto stage = [&](int buf, int kt) {
        char* Ld = (char*)lds + buf * BUFB + (size_t)tid * 16;
#pragma unroll
        for (int p = 0; p < AP; ++p) {
            int row = p * 64 + srow;
            int soct = sobase ^ (row & 7);
            gload_lds16(A + (m0 + row) * (size_t)K + kt * 64 + soct * 8, Ld + p * 8192);
        }
#pragma unroll
        for (int p = 0; p < BP; ++p) {
            int row = p * 64 + srow;
            int soct = sobase ^ (row & 7);
            gload_lds16(Bt + (n0 + row) * (size_t)K + kt * 64 + soct * 8, Ld + ABYTES + p * 8192);
        }
    };

    // read byte offsets (within a buffer): row*128 + ((ks*4+lk8)^l7)*16
    int aoff0 = (wm * (BM / 2) + lrow) * 128 + ((lk8) ^ l7) * 16;            // ks=0; + mf*2048
    int aoff1 = (wm * (BM / 2) + lrow) * 128 + ((4 + lk8) ^ l7) * 16;        // ks=1
    int boff0 = ABYTES + (wn * (BN / 4) + lrow) * 128 + ((lk8) ^ l7) * 16;   // + nf*2048
    int boff1 = ABYTES + (wn * (BN / 4) + lrow) * 128 + ((4 + lk8) ^ l7) * 16;

    int NK = K >> 6;                 // 12 (fc1) / 48 (fc2)
    stage(0, 0);
    for (int t = 0; t < NK; ++t) {
        int buf = t & 1;
        __syncthreads();             // vmcnt drain (free) + WAR fence for restaging buf^1
        if (t + 1 < NK) stage(buf ^ 1, t + 1);
        const char* L = (const char*)lds + buf * BUFB;
        short8 bfr[NF][2];
#pragma unroll
        for (int nf = 0; nf < NF; ++nf) {
            bfr[nf][0] = *(const short8*)(L + boff0 + nf * 2048);
            bfr[nf][1] = *(const short8*)(L + boff1 + nf * 2048);
        }
#pragma unroll
        for (int p = 0; p < MF / 2; ++p) {
            short8 af[2][2];
#pragma unroll
            for (int mh = 0; mh < 2; ++mh) {
                af[mh][0] = *(const short8*)(L + aoff0 + (2 * p + mh) * 2048);
                af[mh][1] = *(const short8*)(L + aoff1 + (2 * p + mh) * 2048);
            }
#pragma unroll
            for (int mh = 0; mh < 2; ++mh)
#pragma unroll
                for (int nf = 0; nf < NF; ++nf) {
                    acc[2 * p + mh][nf] = __builtin_amdgcn_mfma_f32_16x16x32_bf16(
                        af[mh][0], bfr[nf][0], acc[2 * p + mh][nf], 0, 0, 0);
                    acc[2 * p + mh][nf] = __builtin_amdgcn_mfma_f32_16x16x32_bf16(
                        af[mh][1], bfr[nf][1], acc[2 * p + mh][nf], 0, 0, 0);
                }
        }
    }

    int crow = (lane >> 4) * 4;
    int ccol = lane & 15;
#pragma unroll
    for (int mf = 0; mf < MF; ++mf) {
#pragma unroll
        for (int j = 0; j < 4; ++j) {
            size_t r = m0 + wm * (BM / 2) + mf * 16 + crow + j;
            if (EPI == 1 && r >= (size_t)mvalid) continue;
#pragma unroll
            for (int nf = 0; nf < NF; ++nf) {
                size_t cidx = n0 + wn * (BN / 4) + nf * 16 + ccol;
                float v = acc[mf][nf][j] + bias[cidx];
                if (EPI == 0) {
                    obf[r * N + cidx] = __float2bfloat16(gelu_f(v));
                } else {
                    of32[r * N + cidx] = v + res[r * N + cidx];
                }
            }
        }
    }
}

extern "C" void kernel_launch(void* const* d_in, const int* in_sizes, int n_in,
                              void* d_out, int out_size, void* d_ws, size_t ws_size,
                              hipStream_t stream) {
    (void)in_sizes; (void)n_in; (void)out_size;
    const float* x    = (const float*)d_in[0];
    const float* n1w  = (const float*)d_in[1];
    const float* n1b  = (const float*)d_in[2];
    const float* w1   = (const float*)d_in[3];
    const float* b1   = (const float*)d_in[4];
    const float* w2   = (const float*)d_in[5];
    const float* b2   = (const float*)d_in[6];
    const float* n2w  = (const float*)d_in[7];
    const float* n2b  = (const float*)d_in[8];
    const float* fc1w = (const float*)d_in[9];
    const float* fc1b = (const float*)d_in[10];
    const float* fc2w = (const float*)d_in[11];
    const float* fc2b = (const float*)d_in[12];
    float* out = (float*)d_out;

    // ---- tiered chunking over 256-row m-tiles (127 total) ----
    const size_t fl_region1 = (size_t)MPAD * C_ / 2;            // h1/h3 bf16
    const size_t fl_f1      = (size_t)NPOS * C_;                // f1r+f1i bf16
    const size_t fl_tb1     = (size_t)MPAD * HID / 2;           // full-M tb bf16
    const size_t fl_tb2     = (size_t)64 * 256 * HID / 2;       // 64-tile chunk tb
    const size_t fl_wx      = 2712576 + 4096;
    const size_t need1 = (fl_region1 + fl_tb1 + fl_wx) * 4;
    const size_t need2 = (fl_region1 + ((fl_f1 > fl_tb2) ? fl_f1 : fl_tb2) + fl_wx) * 4;
    int nch = (ws_size >= need1) ? 1 : (ws_size >= need2) ? 2 : 4;
    size_t fl_tb = (nch == 1) ? fl_tb1 : (nch == 2) ? fl_tb2 : 0;
    size_t fl_big = (fl_f1 > fl_tb) ? fl_f1 : fl_tb;

    float* wsf = (float*)d_ws;
    size_t off = 0;
    auto alloc = [&](size_t nfloats) { float* p = wsf + off; off += (nfloats + 63) & ~(size_t)63; return p; };
    float* region1   = alloc(fl_region1);     // h1 (bf16) then h3 (bf16)
    float* regionBig = alloc(fl_big);         // f1r,f1i (bf16) then tb (bf16 chunk)
    __hip_bfloat16* w1t = (__hip_bfloat16*)alloc((size_t)HID * C_ / 2);
    __hip_bfloat16* w2t = (__hip_bfloat16*)alloc((size_t)HID * C_ / 2);
    __hip_bfloat16* wbig = (__hip_bfloat16*)alloc((size_t)2 * NBK * 192 * 192 / 2);
    float* bbig = alloc(2 * NBK * 192);
    __hip_bfloat16* Tw  = (__hip_bfloat16*)alloc(192 * 96 / 2);
    __hip_bfloat16* Twf = (__hip_bfloat16*)alloc(96 * 192 / 2);
    __hip_bfloat16* Thf = (__hip_bfloat16*)alloc(192 * 192 / 2);
    __hip_bfloat16* Thi = (__hip_bfloat16*)alloc(192 * 192 / 2);

    __hip_bfloat16* h1b = (__hip_bfloat16*)region1;
    __hip_bfloat16* h3  = (__hip_bfloat16*)region1;
    short* f1r = (short*)regionBig;
    short* f1i = f1r + (size_t)NPOS * C_;
    __hip_bfloat16* tb  = (__hip_bfloat16*)regionBig;

    init_tables_kernel<<<144, 256, 0, stream>>>(Tw, Twf, Thf, Thi);
    wprep_kernel<<<(2 * NBK * 192 * 192 + 255) / 256, 256, 0, stream>>>(w1, b1, w2, b2, wbig, bbig);
    transpose_cvt_kernel<<<dim3(HID / 32, C_ / 32), 256, 0, stream>>>(fc1w, w1t, C_, HID);
    transpose_cvt_kernel<<<dim3(C_ / 32, HID / 32), 256, 0, stream>>>(fc2w, w2t, HID, C_);

    ln_kernel<<<NTOK, 256, 0, stream>>>(x, n1w, n1b, h1b, NTOK);
    wfft_kernel<<<dim3(B_ * H_, 12), 256, 0, stream>>>(h1b, f1r, f1i, Twf);
    hdft_kernel<<<dim3(B_ * WFK, 12), 256, 0, stream>>>(f1r, f1i, Thf);
    blockmlp_mfma_kernel<<<dim3(130, NBK), 256, 0, stream>>>(f1r, f1i, wbig, bbig);
    hdft_kernel<<<dim3(B_ * WFK, 12), 256, 0, stream>>>(f1r, f1i, Thi);
    iwfft_kernel<<<dim3(B_ * H_, 12), 256, 0, stream>>>(f1r, f1i, h1b, x, out, Tw);
    // h1b, f1r/f1i dead from here; regions reused by h3 and tb
    ln_kernel<<<MPAD, 256, 0, stream>>>(out, n2w, n2b, h3, NTOK);

    int tilesArr[4], ntiles = 0;
    if (nch == 1)      { tilesArr[0] = 127; ntiles = 1; }
    else if (nch == 2) { tilesArr[0] = 64; tilesArr[1] = 63; ntiles = 2; }
    else               { tilesArr[0] = 32; tilesArr[1] = 32; tilesArr[2] = 32; tilesArr[3] = 31; ntiles = 4; }
    int baseT = 0;
    for (int c = 0; c < ntiles; ++c) {
        int tiles = tilesArr[c];
        size_t baseRow = (size_t)baseT * 256;
        gemm_kernel<0, 256, 256><<<tiles * (HID / 256), 512, 0, stream>>>(
            (const short*)(h3 + baseRow * C_), (const short*)w1t, fc1b,
            tb, nullptr, nullptr, HID, C_, 0, tiles, HID / 256);
        gemm_kernel<1, 128, 256><<<(tiles * 2) * (C_ / 256), 512, 0, stream>>>(
            (const short*)tb, (const short*)w2t, fc2b,
            nullptr, out + baseRow * C_, out + baseRow * C_, C_, HID, NTOK - (int)baseRow, tiles * 2, C_ / 256);
        baseT += tiles;
    }
}